// Round 11
// baseline (98.049 us; speedup 1.0000x reference)
//
#include <hip/hip_runtime.h>

// SpectralConv2d via pruned partial DFTs (h-DFT first).
// x: [16,32,256,256] f32 ; w1,w2: [32,32,12,12,2] f32 ; out: [16,32,256,256] f32
// Pipeline:
//  K1: Y[bi][cls][w]    = partial H-DFT: C_j[w]=sum_h x cos, S_j[w]=sum_h x sin (j=0..12)
//       (h,h+128) parity fold + phasor rotation. global_load_lds double-buffer with
//       ISSUE-BEFORE-CONSUME ordering (r10 bug: stage issued right before the barrier
//       -> vmcnt(0) drain exposed full latency+transfer serially; T3 recipe fixes it).
//  K2: X[ky][kx][bi]    = partial W-DFT of (C - iS) via per-thread phasor recurrence
//  K3: F[ky][kx][bo]    = channel mix (complex), scale (kx==0?1:2)/65536 folded in
//  K4: G[bo][h][kx]     = inverse ky-DFT; block = one bo, contiguous 1.5KB write bursts
//  K5: out[bo][h][w]    = inverse W-DFT (real output, Hermitian doubling prefolded)

#define TPI 6.28318530717958647692f

#define LOAD_LDS_16(gaddr, laddr)                                              \
  __builtin_amdgcn_global_load_lds(                                            \
      (const __attribute__((address_space(1))) void*)(gaddr),                  \
      (__attribute__((address_space(3))) void*)(laddr), 16, 0, 0)

__global__ __launch_bounds__(256, 2) void k1_hdft(const float* __restrict__ x,
                                                  float* __restrict__ Y) {
  __shared__ float pool[2 * 32 * 256];  // 2 bufs x 32 rows x 1KB = 64 KB
  __shared__ float2 step2[128];         // (cos,sin)(2pi h/256)  (1 KB)
  const int bi = blockIdx.x;            // 0..511
  const int t = threadIdx.x;
  const int q = t >> 6, l = t & 63;     // wave q, lane l

  if (t < 128) {
    float s, c;
    sincosf(TPI * (float)t * (1.0f / 256.0f), &s, &c);
    step2[t] = make_float2(c, s);
  }

  const float* xbi = x + (size_t)bi * 65536;

  // stage chunk c (pairs c*16..c*16+15 -> rows 0..15 low, 16..31 high) into buf c&1.
  auto stage = [&](int c) {
    float* dst = &pool[(c & 1) * 8192];
#pragma unroll
    for (int i = 0; i < 8; i++) {
      int r = q * 8 + i;
      int h = (r < 16) ? (c * 16 + r) : (c * 16 + (r - 16) + 128);
      LOAD_LDS_16(xbi + h * 256 + 4 * l, dst + r * 256);
    }
  };

  float4 aC[13], aS12[12];              // aS12[j-1] holds S_j (S_0 == 0)
#pragma unroll
  for (int j = 0; j < 13; j++) aC[j] = make_float4(0.f, 0.f, 0.f, 0.f);
#pragma unroll
  for (int j = 0; j < 12; j++) aS12[j] = make_float4(0.f, 0.f, 0.f, 0.f);

  stage(0);

  for (int c = 0; c < 8; c++) {
    __syncthreads();                    // drains vmcnt -> chunk c ready; buf[(c+1)&1] free
    if (c < 7) stage(c + 1);            // issue EARLY: transfer overlaps consume(c)
    const float* buf = &pool[(c & 1) * 8192];
    const int pq = q * 4;
#pragma unroll
    for (int i = 0; i < 4; i++) {
      int p = c * 16 + pq + i;          // h of this pair (0..127)
      float4 xa = *reinterpret_cast<const float4*>(&buf[(pq + i) * 256 + 4 * l]);
      float4 xb = *reinterpret_cast<const float4*>(&buf[(16 + pq + i) * 256 + 4 * l]);
      float4 xe = make_float4(xa.x + xb.x, xa.y + xb.y, xa.z + xb.z, xa.w + xb.w);
      float4 xo = make_float4(xa.x - xb.x, xa.y - xb.y, xa.z - xb.z, xa.w - xb.w);
      aC[0].x += xe.x; aC[0].y += xe.y; aC[0].z += xe.z; aC[0].w += xe.w;
      float2 st = step2[p];
      float cj = st.x, sj = st.y;       // phasor at j=1
#pragma unroll
      for (int jj = 0; jj < 12; jj++) { // j = jj+1 in 1..12
        float4 xj = (jj & 1) ? xe : xo; // j odd <=> jj even -> xo
        aC[jj + 1].x = fmaf(xj.x, cj, aC[jj + 1].x);
        aC[jj + 1].y = fmaf(xj.y, cj, aC[jj + 1].y);
        aC[jj + 1].z = fmaf(xj.z, cj, aC[jj + 1].z);
        aC[jj + 1].w = fmaf(xj.w, cj, aC[jj + 1].w);
        aS12[jj].x = fmaf(xj.x, sj, aS12[jj].x);
        aS12[jj].y = fmaf(xj.y, sj, aS12[jj].y);
        aS12[jj].z = fmaf(xj.z, sj, aS12[jj].z);
        aS12[jj].w = fmaf(xj.w, sj, aS12[jj].w);
        if (jj < 11) {
          float nc = fmaf(cj, st.x, -(sj * st.y));
          float ns = fmaf(cj, st.y, sj * st.x);
          cj = nc; sj = ns;
        }
      }
    }
  }

  // cross-wave reduce: 4 passes x 7 classes (cls = 2j for C_j, 2j+1 for S_j); reuse pool
  float* red = pool;
  float* Yb = Y + (size_t)bi * 6656;
  for (int p = 0; p < 4; p++) {
    __syncthreads();
#pragma unroll
    for (int cc = 0; cc < 7; cc++) {
      int cls = p * 7 + cc;
      if (cls < 26) {
        int j = cls >> 1;
        float4 v;
        if (cls & 1) v = (j == 0) ? make_float4(0.f, 0.f, 0.f, 0.f) : aS12[j - 1];
        else v = aC[j];
        *reinterpret_cast<float4*>(&red[(q * 7 + cc) * 256 + 4 * l]) = v;
      }
    }
    __syncthreads();
    for (int idx = t; idx < 7 * 256; idx += 256) {
      int cc = idx >> 8, wl = idx & 255;
      int cls = p * 7 + cc;
      if (cls < 26) {
        float s = red[(0 * 7 + cc) * 256 + wl] + red[(1 * 7 + cc) * 256 + wl] +
                  red[(2 * 7 + cc) * 256 + wl] + red[(3 * 7 + cc) * 256 + wl];
        Yb[cls * 256 + wl] = s;
      }
    }
  }
}

__global__ __launch_bounds__(192) void k2_wdft(const float* __restrict__ Y,
                                               float* __restrict__ Xf) {
  __shared__ float Ys[13 * 514];  // [j][w][{C,S}], stride 514 (bank-spread)
  const int bi = blockIdx.x;
  const int t = threadIdx.x;
  const float* Yg = Y + (size_t)bi * 6656;
  for (int e = t; e < 6656; e += 192) {
    int cls = e >> 8, w = e & 255;
    Ys[(cls >> 1) * 514 + 2 * w + (cls & 1)] = Yg[e];
  }
  __syncthreads();
  if (t >= 156) return;
  int j = t / 12, kx = t % 12;  // j = |ky| 0..12
  float cs, ss;
  {
    float s, c;
    sincosf(TPI * (float)kx * (1.0f / 256.0f), &s, &c);
    cs = c; ss = -s;  // step phasor e^{-i kx theta}
  }
  const float2* CS = reinterpret_cast<const float2*>(&Ys[j * 514]);
  float pr = 1.0f, pi = 0.0f;
  float A = 0, B = 0, D = 0, E = 0;
#pragma unroll 4
  for (int w = 0; w < 256; w++) {
    float2 v = CS[w];
    A = fmaf(v.x, pr, A);
    B = fmaf(v.x, pi, B);
    D = fmaf(v.y, pr, D);
    E = fmaf(v.y, pi, E);
    float npr = pr * cs - pi * ss;
    float npi = pr * ss + pi * cs;
    pr = npr; pi = npi;
  }
  // X[ky=j]     = (C - iS)*t : re = A + E, im = B - D
  // X[ky=256-j] = (C + iS)*t : re = A - E, im = B + D  -> slot 24-j
  float2* Xo = reinterpret_cast<float2*>(Xf);
  size_t base = (size_t)kx * 512 + bi;
  if (j <= 11) Xo[(size_t)j * 12 * 512 + base] = make_float2(A + E, B - D);
  if (j >= 1)  Xo[(size_t)(24 - j) * 12 * 512 + base] = make_float2(A - E, B + D);
}

__global__ __launch_bounds__(256) void k3_mix(const float* __restrict__ Xf,
                                              const float* __restrict__ w1,
                                              const float* __restrict__ w2,
                                              float* __restrict__ Ff) {
  __shared__ float Xs[1024];  // [b][i][2]
  __shared__ float Ws[2048];  // [i][o][2]
  int m = blockIdx.x;         // ky*12 + kx, 288 blocks
  int ky = m / 12, kx = m % 12;
  int t = threadIdx.x;
  const float* Xsl = Xf + (size_t)m * 1024;
  for (int e = t; e < 1024; e += 256) Xs[e] = Xsl[e];
  const float* Wp = (ky < 12) ? w1 : w2;
  int myr = (ky < 12) ? ky : ky - 12;
  int woff = myr * 24 + kx * 2;
  for (int e = t; e < 1024; e += 256) {  // e = i*32 + o
    float2 wv = *reinterpret_cast<const float2*>(Wp + (size_t)e * 288 + woff);
    Ws[e * 2] = wv.x; Ws[e * 2 + 1] = wv.y;
  }
  __syncthreads();
  int o = t & 31, bh = t >> 5;  // bh 0..7 ; handles b = bh and bh+8
  float ar = 0, ai = 0, br = 0, bi_ = 0;
#pragma unroll
  for (int i = 0; i < 32; i++) {
    float wr = Ws[i * 64 + o * 2], wi = Ws[i * 64 + o * 2 + 1];
    float x1r = Xs[bh * 64 + i * 2], x1i = Xs[bh * 64 + i * 2 + 1];
    float x2r = Xs[(bh + 8) * 64 + i * 2], x2i = Xs[(bh + 8) * 64 + i * 2 + 1];
    ar = fmaf(x1r, wr, ar); ar = fmaf(-x1i, wi, ar);
    ai = fmaf(x1r, wi, ai); ai = fmaf(x1i, wr, ai);
    br = fmaf(x2r, wr, br); br = fmaf(-x2i, wi, br);
    bi_ = fmaf(x2r, wi, bi_); bi_ = fmaf(x2i, wr, bi_);
  }
  float scale = (kx == 0 ? 1.0f : 2.0f) * (1.0f / 65536.0f);
  float2* Fo = reinterpret_cast<float2*>(Ff) + (size_t)m * 512;
  Fo[(size_t)bh * 32 + o] = make_float2(ar * scale, ai * scale);
  Fo[(size_t)(bh + 8) * 32 + o] = make_float2(br * scale, bi_ * scale);
}

__global__ __launch_bounds__(192) void k4_ihdft(const float* __restrict__ Ff,
                                                float* __restrict__ G) {
  __shared__ float tw[128 * 27];      // [h][2j+{c,s}], pad 27 (bank-spread)  13.8 KB
  __shared__ float PQ[13 * 12 * 4];   // [j][kx][{Pr,Pi,Qr,Qi}]  2.4 KB
  const int bo = blockIdx.x;          // 0..511
  const int t = threadIdx.x;          // 0..191

  for (int e = t; e < 128 * 13; e += 192) {
    int h = e / 13, j = e % 13;
    float s, c;
    sincosf(TPI * (float)((h * j) & 255) * (1.0f / 256.0f), &s, &c);
    tw[h * 27 + 2 * j] = c;
    tw[h * 27 + 2 * j + 1] = s;
  }
  if (t < 156) {
    int j = t / 12, kx = t % 12;
    const float2* F2 = reinterpret_cast<const float2*>(Ff);
    float lr = 0, li = 0, hr = 0, hi = 0;
    if (j < 12) { float2 v = F2[((size_t)j * 12 + kx) * 512 + bo]; lr = v.x; li = v.y; }
    if (j > 0)  { float2 v = F2[((size_t)(24 - j) * 12 + kx) * 512 + bo]; hr = v.x; hi = v.y; }
    PQ[(j * 12 + kx) * 4 + 0] = lr + hr;  // Pr
    PQ[(j * 12 + kx) * 4 + 1] = li + hi;  // Pi
    PQ[(j * 12 + kx) * 4 + 2] = hi - li;  // Qr
    PQ[(j * 12 + kx) * 4 + 3] = lr - hr;  // Qi
  }
  __syncthreads();

  const int kx = t % 12, hq = t / 12;  // hq 0..15
  float Pr[13], Pi[13], Qr[13], Qi[13];
#pragma unroll
  for (int j = 0; j < 13; j++) {
    Pr[j] = PQ[(j * 12 + kx) * 4 + 0];
    Pi[j] = PQ[(j * 12 + kx) * 4 + 1];
    Qr[j] = PQ[(j * 12 + kx) * 4 + 2];
    Qi[j] = PQ[(j * 12 + kx) * 4 + 3];
  }
  float2* Go = reinterpret_cast<float2*>(G) + (size_t)bo * 3072;
  for (int hh = 0; hh < 8; hh++) {
    int h = hh * 16 + hq;  // 0..127
    float Er = 0, Ei = 0, Or = 0, Oi = 0;  // even-j / odd-j partial sums
#pragma unroll
    for (int j = 0; j < 13; j++) {
      float c = tw[h * 27 + 2 * j], s = tw[h * 27 + 2 * j + 1];
      if (j & 1) {
        Or = fmaf(Pr[j], c, Or); Or = fmaf(Qr[j], s, Or);
        Oi = fmaf(Pi[j], c, Oi); Oi = fmaf(Qi[j], s, Oi);
      } else {
        Er = fmaf(Pr[j], c, Er); Er = fmaf(Qr[j], s, Er);
        Ei = fmaf(Pi[j], c, Ei); Ei = fmaf(Qi[j], s, Ei);
      }
    }
    // G[h] = E + O ; G[h+128] = E - O ; writes contiguous: h*12+kx = hh*192 + t
    Go[h * 12 + kx] = make_float2(Er + Or, Ei + Oi);
    Go[(h + 128) * 12 + kx] = make_float2(Er - Or, Ei - Oi);
  }
}

__global__ __launch_bounds__(256) void k5_iwdft(const float* __restrict__ G,
                                                float* __restrict__ out) {
  __shared__ float Gs[64 * 24];
  int blk = blockIdx.x;  // 2048 blocks x 64 rows
  int t = threadIdx.x;
  int l = t & 63, wq = t >> 6;
  size_t row0 = (size_t)blk * 64;
  for (int e = t; e < 1536; e += 256) Gs[e] = G[row0 * 24 + e];
  // lane handles w0 = 2l, w1 = 2l+1 (and +128 partners via parity) -> float2 stores
  float cA[12], sA[12], cB[12], sB[12];
#pragma unroll
  for (int kx = 1; kx < 12; kx++) {
    float s, c;
    __sincosf(TPI * (float)((kx * (2 * l)) & 255) * (1.0f / 256.0f), &s, &c);
    cA[kx] = c; sA[kx] = s;
    __sincosf(TPI * (float)((kx * (2 * l + 1)) & 255) * (1.0f / 256.0f), &s, &c);
    cB[kx] = c; sB[kx] = s;
  }
  __syncthreads();
  for (int rs = 0; rs < 16; rs++) {
    int rl = wq * 16 + rs;
    float g[24];
    const float4* gr4 = reinterpret_cast<const float4*>(&Gs[rl * 24]);
#pragma unroll
    for (int q = 0; q < 6; q++) {
      float4 v = gr4[q];
      g[4 * q] = v.x; g[4 * q + 1] = v.y; g[4 * q + 2] = v.z; g[4 * q + 3] = v.w;
    }
    float E0 = g[0], O0 = 0, E1 = g[0], O1 = 0;  // DC: Re(G0) only (irfft ignores Im)
#pragma unroll
    for (int kx = 1; kx < 12; kx++) {
      float ta = g[2 * kx] * cA[kx] - g[2 * kx + 1] * sA[kx];
      float tb = g[2 * kx] * cB[kx] - g[2 * kx + 1] * sB[kx];
      if (kx & 1) { O0 += ta; O1 += tb; } else { E0 += ta; E1 += tb; }
    }
    size_t ob = (row0 + rl) * 256;
    *reinterpret_cast<float2*>(&out[ob + 2 * l]) = make_float2(E0 + O0, E1 + O1);
    *reinterpret_cast<float2*>(&out[ob + 128 + 2 * l]) = make_float2(E0 - O0, E1 - O1);
  }
}

extern "C" void kernel_launch(void* const* d_in, const int* in_sizes, int n_in,
                              void* d_out, int out_size, void* d_ws, size_t ws_size,
                              hipStream_t stream) {
  const float* x = (const float*)d_in[0];
  const float* w1 = (const float*)d_in[1];
  const float* w2 = (const float*)d_in[2];
  float* out = (float*)d_out;
  float* ws = (float*)d_ws;

  float* Y = ws;                        // 3,407,872 floats (13.6 MB)
  float* Xf = ws + 3407872;             //   294,912 floats
  float* Ff = ws + 3407872 + 294912;    //   294,912 floats
  float* G = ws;                        // reuse Y space (dead after k2)

  k1_hdft<<<512, 256, 0, stream>>>(x, Y);
  k2_wdft<<<512, 192, 0, stream>>>(Y, Xf);
  k3_mix<<<288, 256, 0, stream>>>(Xf, w1, w2, Ff);
  k4_ihdft<<<512, 192, 0, stream>>>(Ff, G);
  k5_iwdft<<<2048, 256, 0, stream>>>(G, out);
}

// Round 12
// 81.690 us; speedup vs baseline: 1.2003x; 1.2003x over previous
//
#include <hip/hip_runtime.h>

// SpectralConv2d via pruned partial DFTs (h-DFT first), 3-kernel fused pipeline.
// x: [16,32,256,256] f32 ; w1,w2: [32,32,12,12,2] f32 ; out: [16,32,256,256] f32
//  K12: per (bi, w-half) block: partial H-DFT (parity fold + phasor rotation, r6's
//       proven no-spill body) reduced into LDS, then K2's w-DFT phasor loop runs
//       in-block on the LDS rows -> partial Xf[wh] (no Y round-trip, no K2 launch).
//       Half-range w-sum fixed up by (-1)^(kx*wh).
//  K3:  F[ky][kx][bo] = channel mix (complex); sums the two Xf halves at load;
//       scale (kx==0?1:2)/65536 folded in.
//  K45: per bo block: inverse ky-DFT -> G[bo] in LDS (24KB), then inverse w-DFT
//       from LDS -> out (no G round-trip, no extra launch).

#define TPI 6.28318530717958647692f

__global__ __launch_bounds__(256, 2) void k12_hwdft(const float* __restrict__ x,
                                                    float* __restrict__ Xf) {
  __shared__ float2 step2[128];       // (cos,sin)(2pi h/256)  (1 KB)
  __shared__ float red[4 * 7 * 128];  // cross-wave reduce (14 KB)
  __shared__ float2 Ys2[13 * 129];    // [j][w-local] {C,S}, pad 129 (13.4 KB)
  const int blk = blockIdx.x;         // 0..1023 = bi*2 + wh
  const int bi = blk >> 1, wh = blk & 1;
  const int t = threadIdx.x;
  const int q = t >> 6, l = t & 63;   // wave q -> 32 h-pairs, lane l -> w = wh*128 + 2l{,+1}

  if (t < 128) {
    float s, c;
    sincosf(TPI * (float)t * (1.0f / 256.0f), &s, &c);
    step2[t] = make_float2(c, s);
  }
  __syncthreads();

  const float2* xp2 = reinterpret_cast<const float2*>(x + (size_t)bi * 65536 + wh * 128) + l;
  float2 aC[13], aS12[12];            // aS12[j-1] holds S_j (S_0 == 0 identically)
#pragma unroll
  for (int j = 0; j < 13; j++) aC[j] = make_float2(0.f, 0.f);
#pragma unroll
  for (int j = 0; j < 12; j++) aS12[j] = make_float2(0.f, 0.f);

  const int h0 = q * 32;
#pragma unroll 2
  for (int hh = 0; hh < 32; hh++) {
    int h = h0 + hh;
    float2 xa = xp2[h * 128];          // row stride = 128 float2
    float2 xb = xp2[(h + 128) * 128];
    float2 xe = make_float2(xa.x + xb.x, xa.y + xb.y);
    float2 xo = make_float2(xa.x - xb.x, xa.y - xb.y);
    aC[0].x += xe.x; aC[0].y += xe.y;  // j=0: cos=1, sin=0
    float2 st = step2[h];
    float cj = st.x, sj = st.y;        // phasor at j=1
#pragma unroll
    for (int jj = 0; jj < 12; jj++) {  // j = jj+1 in 1..12
      float2 xj = (jj & 1) ? xe : xo;  // j odd <=> jj even -> xo
      aC[jj + 1].x = fmaf(xj.x, cj, aC[jj + 1].x);
      aC[jj + 1].y = fmaf(xj.y, cj, aC[jj + 1].y);
      aS12[jj].x = fmaf(xj.x, sj, aS12[jj].x);
      aS12[jj].y = fmaf(xj.y, sj, aS12[jj].y);
      if (jj < 11) {
        float nc = fmaf(cj, st.x, -(sj * st.y));  // rotate by e^{i th_h}
        float ns = fmaf(cj, st.y, sj * st.x);
        cj = nc; sj = ns;
      }
    }
  }

  // cross-wave reduce into LDS Ys2 (no global Y): 4 passes x 7 classes
  for (int p = 0; p < 4; p++) {
    __syncthreads();
#pragma unroll
    for (int cc = 0; cc < 7; cc++) {
      int cls = p * 7 + cc;
      if (cls < 26) {
        int j = cls >> 1;
        float2 v;
        if (cls & 1) v = (j == 0) ? make_float2(0.f, 0.f) : aS12[j - 1];
        else v = aC[j];
        *reinterpret_cast<float2*>(&red[(q * 7 + cc) * 128 + 2 * l]) = v;
      }
    }
    __syncthreads();
    for (int idx = t; idx < 7 * 128; idx += 256) {
      int cc = idx >> 7, wl = idx & 127;
      int cls = p * 7 + cc;
      if (cls < 26) {
        float s = red[(0 * 7 + cc) * 128 + wl] + red[(1 * 7 + cc) * 128 + wl] +
                  red[(2 * 7 + cc) * 128 + wl] + red[(3 * 7 + cc) * 128 + wl];
        if (cls & 1) Ys2[(cls >> 1) * 129 + wl].y = s;
        else         Ys2[(cls >> 1) * 129 + wl].x = s;
      }
    }
  }
  __syncthreads();

  // K2 phase in-block: partial w-DFT over this half's 128 w's
  if (t < 156) {
    int j = t / 12, kx = t % 12;  // j = |ky| 0..12
    float cs, ss;
    {
      float s, c;
      sincosf(TPI * (float)kx * (1.0f / 256.0f), &s, &c);
      cs = c; ss = -s;  // step phasor e^{-i kx theta}
    }
    const float2* CS = &Ys2[j * 129];
    float pr = 1.0f, pi = 0.0f;
    float A = 0, B = 0, D = 0, E = 0;
#pragma unroll 4
    for (int w = 0; w < 128; w++) {
      float2 v = CS[w];
      A = fmaf(v.x, pr, A);
      B = fmaf(v.x, pi, B);
      D = fmaf(v.y, pr, D);
      E = fmaf(v.y, pi, E);
      float npr = pr * cs - pi * ss;
      float npi = pr * ss + pi * cs;
      pr = npr; pi = npi;
    }
    // global w = wh*128 + w'  ->  multiply by (-1)^(kx*wh)
    float sgn = (wh && (kx & 1)) ? -1.0f : 1.0f;
    A *= sgn; B *= sgn; D *= sgn; E *= sgn;
    // X[ky=j] partial: re = A + E, im = B - D ; X[24-j]: re = A - E, im = B + D
    float2* Xo = reinterpret_cast<float2*>(Xf) + (size_t)wh * 147456;
    size_t base = (size_t)kx * 512 + bi;
    if (j <= 11) Xo[(size_t)j * 6144 + base] = make_float2(A + E, B - D);
    if (j >= 1)  Xo[(size_t)(24 - j) * 6144 + base] = make_float2(A - E, B + D);
  }
}

__global__ __launch_bounds__(256) void k3_mix(const float* __restrict__ Xf,
                                              const float* __restrict__ w1,
                                              const float* __restrict__ w2,
                                              float* __restrict__ Ff) {
  __shared__ float Xs[1024];  // [b][i][2]
  __shared__ float Ws[2048];  // [i][o][2]
  int m = blockIdx.x;         // ky*12 + kx, 288 blocks
  int ky = m / 12, kx = m % 12;
  int t = threadIdx.x;
  const float* Xsl = Xf + (size_t)m * 1024;
  for (int e = t; e < 1024; e += 256) Xs[e] = Xsl[e] + Xsl[e + 294912];  // sum halves
  const float* Wp = (ky < 12) ? w1 : w2;
  int myr = (ky < 12) ? ky : ky - 12;
  int woff = myr * 24 + kx * 2;
  for (int e = t; e < 1024; e += 256) {  // e = i*32 + o
    float2 wv = *reinterpret_cast<const float2*>(Wp + (size_t)e * 288 + woff);
    Ws[e * 2] = wv.x; Ws[e * 2 + 1] = wv.y;
  }
  __syncthreads();
  int o = t & 31, bh = t >> 5;  // bh 0..7 ; handles b = bh and bh+8
  float ar = 0, ai = 0, br = 0, bi_ = 0;
#pragma unroll
  for (int i = 0; i < 32; i++) {
    float wr = Ws[i * 64 + o * 2], wi = Ws[i * 64 + o * 2 + 1];
    float x1r = Xs[bh * 64 + i * 2], x1i = Xs[bh * 64 + i * 2 + 1];
    float x2r = Xs[(bh + 8) * 64 + i * 2], x2i = Xs[(bh + 8) * 64 + i * 2 + 1];
    ar = fmaf(x1r, wr, ar); ar = fmaf(-x1i, wi, ar);
    ai = fmaf(x1r, wi, ai); ai = fmaf(x1i, wr, ai);
    br = fmaf(x2r, wr, br); br = fmaf(-x2i, wi, br);
    bi_ = fmaf(x2r, wi, bi_); bi_ = fmaf(x2i, wr, bi_);
  }
  float scale = (kx == 0 ? 1.0f : 2.0f) * (1.0f / 65536.0f);
  float2* Fo = reinterpret_cast<float2*>(Ff) + (size_t)m * 512;
  Fo[(size_t)bh * 32 + o] = make_float2(ar * scale, ai * scale);
  Fo[(size_t)(bh + 8) * 32 + o] = make_float2(br * scale, bi_ * scale);
}

__global__ __launch_bounds__(256) void k45_inv(const float* __restrict__ Ff,
                                               float* __restrict__ out) {
  __shared__ float tw[128 * 27];     // [h][2j+{c,s}], pad 27 (13.8 KB)
  __shared__ float PQ[13 * 12 * 4];  // [j][kx][{Pr,Pi,Qr,Qi}] (2.4 KB)
  __shared__ float Gs[256 * 24];     // G[bo] rows (24.6 KB)
  const int bo = blockIdx.x;         // 0..511
  const int t = threadIdx.x;         // 0..255
  const int l = t & 63, wq = t >> 6;

  for (int e = t; e < 128 * 13; e += 256) {
    int h = e / 13, j = e % 13;
    float s, c;
    sincosf(TPI * (float)((h * j) & 255) * (1.0f / 256.0f), &s, &c);
    tw[h * 27 + 2 * j] = c;
    tw[h * 27 + 2 * j + 1] = s;
  }
  if (t < 156) {
    int j = t / 12, kx = t % 12;
    const float2* F2 = reinterpret_cast<const float2*>(Ff);
    float lr = 0, li = 0, hr = 0, hi = 0;
    if (j < 12) { float2 v = F2[((size_t)j * 12 + kx) * 512 + bo]; lr = v.x; li = v.y; }
    if (j > 0)  { float2 v = F2[((size_t)(24 - j) * 12 + kx) * 512 + bo]; hr = v.x; hi = v.y; }
    PQ[(j * 12 + kx) * 4 + 0] = lr + hr;  // Pr
    PQ[(j * 12 + kx) * 4 + 1] = li + hi;  // Pi
    PQ[(j * 12 + kx) * 4 + 2] = hi - li;  // Qr
    PQ[(j * 12 + kx) * 4 + 3] = lr - hr;  // Qi
  }
  __syncthreads();

  // Phase A: inverse ky-DFT -> Gs (t < 192: 16 hq x 12 kx)
  if (t < 192) {
    const int kx = t % 12, hq = t / 12;  // hq 0..15
    float Pr[13], Pi[13], Qr[13], Qi[13];
#pragma unroll
    for (int j = 0; j < 13; j++) {
      Pr[j] = PQ[(j * 12 + kx) * 4 + 0];
      Pi[j] = PQ[(j * 12 + kx) * 4 + 1];
      Qr[j] = PQ[(j * 12 + kx) * 4 + 2];
      Qi[j] = PQ[(j * 12 + kx) * 4 + 3];
    }
    for (int hh = 0; hh < 8; hh++) {
      int h = hh * 16 + hq;  // 0..127
      float Er = 0, Ei = 0, Or = 0, Oi = 0;
#pragma unroll
      for (int j = 0; j < 13; j++) {
        float c = tw[h * 27 + 2 * j], s = tw[h * 27 + 2 * j + 1];
        if (j & 1) {
          Or = fmaf(Pr[j], c, Or); Or = fmaf(Qr[j], s, Or);
          Oi = fmaf(Pi[j], c, Oi); Oi = fmaf(Qi[j], s, Oi);
        } else {
          Er = fmaf(Pr[j], c, Er); Er = fmaf(Qr[j], s, Er);
          Ei = fmaf(Pi[j], c, Ei); Ei = fmaf(Qi[j], s, Ei);
        }
      }
      Gs[h * 24 + 2 * kx] = Er + Or;           // G[h]
      Gs[h * 24 + 2 * kx + 1] = Ei + Oi;
      Gs[(h + 128) * 24 + 2 * kx] = Er - Or;   // G[h+128]
      Gs[(h + 128) * 24 + 2 * kx + 1] = Ei - Oi;
    }
  }

  // Phase B twiddles (independent of Gs -> before barrier)
  float cA[12], sA[12], cB[12], sB[12];
#pragma unroll
  for (int kx = 1; kx < 12; kx++) {
    float s, c;
    __sincosf(TPI * (float)((kx * (2 * l)) & 255) * (1.0f / 256.0f), &s, &c);
    cA[kx] = c; sA[kx] = s;
    __sincosf(TPI * (float)((kx * (2 * l + 1)) & 255) * (1.0f / 256.0f), &s, &c);
    cB[kx] = c; sB[kx] = s;
  }
  __syncthreads();

  // Phase B: inverse w-DFT from Gs; wave wq owns rows wq*64..wq*64+63
  float* ob0 = out + ((size_t)bo * 256 + wq * 64) * 256;
  for (int rs = 0; rs < 64; rs++) {
    int rl = wq * 64 + rs;
    float g[24];
    const float4* gr4 = reinterpret_cast<const float4*>(&Gs[rl * 24]);
#pragma unroll
    for (int qq = 0; qq < 6; qq++) {
      float4 v = gr4[qq];
      g[4 * qq] = v.x; g[4 * qq + 1] = v.y; g[4 * qq + 2] = v.z; g[4 * qq + 3] = v.w;
    }
    float E0 = g[0], O0 = 0, E1 = g[0], O1 = 0;  // DC: Re(G0) only
#pragma unroll
    for (int kx = 1; kx < 12; kx++) {
      float ta = g[2 * kx] * cA[kx] - g[2 * kx + 1] * sA[kx];
      float tb = g[2 * kx] * cB[kx] - g[2 * kx + 1] * sB[kx];
      if (kx & 1) { O0 += ta; O1 += tb; } else { E0 += ta; E1 += tb; }
    }
    float* orow = ob0 + rs * 256;
    *reinterpret_cast<float2*>(&orow[2 * l]) = make_float2(E0 + O0, E1 + O1);
    *reinterpret_cast<float2*>(&orow[128 + 2 * l]) = make_float2(E0 - O0, E1 - O1);
  }
}

extern "C" void kernel_launch(void* const* d_in, const int* in_sizes, int n_in,
                              void* d_out, int out_size, void* d_ws, size_t ws_size,
                              hipStream_t stream) {
  const float* x = (const float*)d_in[0];
  const float* w1 = (const float*)d_in[1];
  const float* w2 = (const float*)d_in[2];
  float* out = (float*)d_out;
  float* ws = (float*)d_ws;

  float* Xf = ws;               // 2 x 294,912 floats (partial halves)
  float* Ff = ws + 589824;      //     294,912 floats

  k12_hwdft<<<1024, 256, 0, stream>>>(x, Xf);
  k3_mix<<<288, 256, 0, stream>>>(Xf, w1, w2, Ff);
  k45_inv<<<512, 256, 0, stream>>>(Ff, out);
}